// Round 6
// baseline (762.433 us; speedup 1.0000x reference)
//
#include <hip/hip_runtime.h>
#include <hip/hip_fp16.h>

#define NN 64000
#define ET 1024000

typedef __attribute__((ext_vector_type(8))) short short8;

__device__ inline float h2f(__half h) { return __half2float(h); }
__device__ inline float dec_w(unsigned p) {
  return __half2float(__ushort_as_half((unsigned short)(p >> 16)));
}

// ---------------- graph build ----------------

__global__ void k_deg(const int* __restrict__ ei, int* __restrict__ deg) {
  int e = blockIdx.x * 256 + threadIdx.x;
  if (e < ET) atomicAdd(&deg[ei[e]], 1);
}

__global__ void k_scan1(const int* __restrict__ deg, float* __restrict__ dis,
                        int* __restrict__ rowp, int* __restrict__ bsum) {
  __shared__ int buf[256];
  int t = threadIdx.x;
  int idx = blockIdx.x * 256 + t;
  int v = deg[idx];
  dis[idx] = v > 0 ? rsqrtf((float)v) : 0.f;
  buf[t] = v;
  __syncthreads();
  for (int off = 1; off < 256; off <<= 1) {
    int x = (t >= off) ? buf[t - off] : 0;
    __syncthreads();
    buf[t] += x;
    __syncthreads();
  }
  rowp[idx] = buf[t] - v;
  if (t == 255) bsum[blockIdx.x] = buf[t];
}

__global__ void k_scan2(const int* __restrict__ bsum, int* __restrict__ boff) {
  __shared__ int buf[256];
  int t = threadIdx.x;
  int v = (t < 250) ? bsum[t] : 0;
  buf[t] = v;
  __syncthreads();
  for (int off = 1; off < 256; off <<= 1) {
    int x = (t >= off) ? buf[t - off] : 0;
    __syncthreads();
    buf[t] += x;
    __syncthreads();
  }
  if (t < 250) boff[t] = buf[t] - v;
}

__global__ void k_scan3(int* __restrict__ rowp, const int* __restrict__ boff,
                        int* __restrict__ fillp) {
  int idx = blockIdx.x * 256 + threadIdx.x;
  int v = rowp[idx] + boff[blockIdx.x];
  rowp[idx] = v;
  fillp[idx] = v;
  if (idx == 0) rowp[NN] = ET;
}

// packed edge record: low16 = src node, high16 = f16 norm
__global__ void k_fill(const int* __restrict__ ei, const float* __restrict__ dis,
                       int* __restrict__ fill_ptr, unsigned* __restrict__ edata) {
  int e = blockIdx.x * 256 + threadIdx.x;
  if (e >= ET) return;
  int s = ei[e];
  int d = ei[ET + e];
  float nrm = -dis[s] * dis[d];
  unsigned packed = (unsigned)s |
      ((unsigned)__half_as_ushort(__float2half(nrm)) << 16);
  int p = atomicAdd(&fill_ptr[d], 1);
  edata[p] = packed;
}

// ---------------- Chebyshev weight fold ----------------
// out = h*W0 + T1*W1 + (2*L*T1 - h)*W2 == h*(W0-W2) + T1*W1 + (L*T1)*(2*W2)

struct WXArgs {
  const float *s0, *s1, *s2, *s3, *s4, *s5;
  float *d0, *d1, *d2, *d3, *d4, *d5;
};

__global__ void k_wx(WXArgs a) {
  int b = blockIdx.x;
  int set = b >> 4;
  const float* s;
  float* d;
  int n = (set < 5) ? 4096 : 64;
  switch (set) {
    case 0: s = a.s0; d = a.d0; break;
    case 1: s = a.s1; d = a.d1; break;
    case 2: s = a.s2; d = a.d2; break;
    case 3: s = a.s3; d = a.d3; break;
    case 4: s = a.s4; d = a.d4; break;
    default: s = a.s5; d = a.d5; break;
  }
  int i = (set < 5) ? (b - set * 16) * 256 + threadIdx.x : threadIdx.x;
  if (i < n) {
    d[i]         = s[i] - s[i + 2 * n];
    d[i + n]     = s[i + n];
    d[i + 2 * n] = 2.f * s[i + 2 * n];
  }
}

// ---------------- scalar (1-channel) plain prop for layer 1 (f32) ----------

__global__ void k_prop_s(const float* __restrict__ in, const int* __restrict__ row_ptr,
                         const unsigned* __restrict__ edata, float* __restrict__ out) {
  int n = blockIdx.x * 256 + threadIdx.x;
  if (n >= NN) return;
  int s = row_ptr[n], e = row_ptr[n + 1];
  float acc = 0.f;
  int j = s;
  for (; j + 4 <= e; j += 4) {
    unsigned e0 = edata[j], e1 = edata[j + 1], e2 = edata[j + 2], e3 = edata[j + 3];
    acc += in[e0 & 0xFFFFu] * dec_w(e0) + in[e1 & 0xFFFFu] * dec_w(e1) +
           in[e2 & 0xFFFFu] * dec_w(e2) + in[e3 & 0xFFFFu] * dec_w(e3);
  }
  for (; j < e; ++j) {
    unsigned e0 = edata[j];
    acc += in[e0 & 0xFFFFu] * dec_w(e0);
  }
  out[n] = acc;
}

__global__ void k_layer1(const float* __restrict__ x, const float* __restrict__ t1,
                         const float* __restrict__ g2, const float* __restrict__ w,
                         const float* __restrict__ b, __half* __restrict__ out) {
  int t = threadIdx.x;
  int node = blockIdx.x * 4 + (t >> 6);
  int f = t & 63;
  float v = x[node] * w[f] + t1[node] * w[64 + f] + g2[node] * w[128 + f] + b[f];
  out[(size_t)node * 64 + f] = __float2half(fmaxf(v, 0.f));
}

// ---------------- 64-ch plain prop: wave per node, 2 edges per gather ------
// lanes 0-31 handle even edges, 32-63 odd; lane loads uint = 2 fp16 feats.
// 256 B per gather instruction, half the instruction count.

__global__ __launch_bounds__(256) void k_prop64(const __half* __restrict__ in,
    const int* __restrict__ row_ptr, const unsigned* __restrict__ edata,
    __half* __restrict__ out) {
  int node = __builtin_amdgcn_readfirstlane(blockIdx.x * 4 + (threadIdx.x >> 6));
  int lane = threadIdx.x & 63;
  int sub = lane >> 5;   // which edge of the pair
  int fp = lane & 31;    // feature pair: features 2fp, 2fp+1
  int s = row_ptr[node], e = row_ptr[node + 1];
  float a0[8], a1[8];
#pragma unroll
  for (int i = 0; i < 8; ++i) { a0[i] = 0.f; a1[i] = 0.f; }
  int j = s;
  for (; j + 16 <= e; j += 16) {
    unsigned ed[8];
#pragma unroll
    for (int i = 0; i < 8; ++i) {
      unsigned p0 = edata[j + 2 * i];      // wave-uniform (s_load)
      unsigned p1 = edata[j + 2 * i + 1];
      ed[i] = sub ? p1 : p0;
    }
    unsigned v[8];
#pragma unroll
    for (int i = 0; i < 8; ++i)
      v[i] = *(const unsigned*)&in[(size_t)(ed[i] & 0xFFFFu) * 64 + fp * 2];
#pragma unroll
    for (int i = 0; i < 8; ++i) {
      float w = dec_w(ed[i]);
      float2 f = __half22float2(*(__half2*)&v[i]);
      a0[i] += f.x * w;
      a1[i] += f.y * w;
    }
  }
  for (; j + 2 <= e; j += 2) {
    unsigned p0 = edata[j], p1 = edata[j + 1];
    unsigned ed = sub ? p1 : p0;
    unsigned v = *(const unsigned*)&in[(size_t)(ed & 0xFFFFu) * 64 + fp * 2];
    float w = dec_w(ed);
    float2 f = __half22float2(*(__half2*)&v);
    a0[0] += f.x * w;
    a1[0] += f.y * w;
  }
  if (j < e) {
    unsigned p0 = edata[j];
    float w = sub ? 0.f : dec_w(p0);
    unsigned v = *(const unsigned*)&in[(size_t)(p0 & 0xFFFFu) * 64 + fp * 2];
    float2 f = __half22float2(*(__half2*)&v);
    a0[0] += f.x * w;
    a1[0] += f.y * w;
  }
#pragma unroll
  for (int i = 0; i < 4; ++i) { a0[i] += a0[i + 4]; a1[i] += a1[i + 4]; }
  float acc0 = (a0[0] + a0[1]) + (a0[2] + a0[3]);
  float acc1 = (a1[0] + a1[1]) + (a1[2] + a1[3]);
  acc0 += __shfl_xor(acc0, 32);
  acc1 += __shfl_xor(acc1, 32);
  if (sub == 0) {
    __half2 h = __floats2half2_rn(acc0, acc1);
    *(unsigned*)&out[(size_t)node * 64 + fp * 2] = *(unsigned*)&h;
  }
}

// ------- fused cheb matmul: out = T0@W0' + T1@W1' + G2@W2' (+b, relu/res), f16 IO

template<int RELU, int RES>
__global__ __launch_bounds__(256) void k_mat64(
    const __half* __restrict__ T0, const __half* __restrict__ T1,
    const __half* __restrict__ T2, const float* __restrict__ W,
    const float* __restrict__ bias, const __half* __restrict__ res,
    __half* __restrict__ out) {
  __shared__ float Ws[3 * 64 * 64];
  __shared__ float As[256 * 21];
  int t = threadIdx.x;
  int node0 = blockIdx.x * 256;
  {
    const float4* Wv = (const float4*)W;
    float4* Sv = (float4*)Ws;
    for (int i = t; i < 3072; i += 256) Sv[i] = Wv[i];
  }
  int fi = t & 7;
  int ni = t >> 3;
  float acc[8][8];
#pragma unroll
  for (int j = 0; j < 8; ++j)
#pragma unroll
    for (int m = 0; m < 8; ++m) acc[j][m] = 0.f;

  for (int p = 0; p < 12; ++p) {
    int k = p >> 2, c0 = (p & 3) << 4;
    const __half* Tsel = (k == 0) ? T0 : (k == 1) ? T1 : T2;
    const __half* src = Tsel + (size_t)(node0 + t) * 64 + c0;
    short8 r0 = *(const short8*)(src);
    short8 r1 = *(const short8*)(src + 8);
    __syncthreads();
    float* dst = &As[t * 21];
#pragma unroll
    for (int i = 0; i < 8; ++i) dst[i] = h2f(__ushort_as_half((unsigned short)r0[i]));
#pragma unroll
    for (int i = 0; i < 8; ++i) dst[8 + i] = h2f(__ushort_as_half((unsigned short)r1[i]));
    __syncthreads();
#pragma unroll
    for (int cc = 0; cc < 16; ++cc) {
      int c = c0 + cc;
      float a[8], bb[8];
#pragma unroll
      for (int j = 0; j < 8; ++j) a[j] = As[(ni + 32 * j) * 21 + cc];
      const float* wrow = &Ws[k * 4096 + c * 64];
#pragma unroll
      for (int m = 0; m < 8; ++m) bb[m] = wrow[fi + 8 * m];
#pragma unroll
      for (int j = 0; j < 8; ++j)
#pragma unroll
        for (int m = 0; m < 8; ++m) acc[j][m] += a[j] * bb[m];
    }
  }
#pragma unroll
  for (int j = 0; j < 8; ++j) {
    int node = node0 + ni + 32 * j;
#pragma unroll
    for (int m = 0; m < 8; ++m) {
      int f = fi + 8 * m;
      float v = acc[j][m] + bias[f];
      if (RES) v += h2f(res[(size_t)node * 64 + f]);
      if (RELU) v = fmaxf(v, 0.f);
      out[(size_t)node * 64 + f] = __float2half(v);
    }
  }
}

// ---------------- readout ----------------
// lin1 partials: C[o][g] = sum_k W[o][k] * H[g][k].  H fp16, W f32.
// grid = 8 o-blocks x 250 k-splits (256 k each); Ktile=64; XOR-swizzled
// LDS (g' = g ^ ((k>>4)<<2), no pad) -> 2-way banks everywhere.

__global__ __launch_bounds__(256) void k_lin1(const __half* __restrict__ H,
    const float* __restrict__ W, float* __restrict__ r1p) {
  __shared__ __align__(16) float As[64 * 64];  // [k][o] swizzled
  __shared__ __align__(16) float Bs[64 * 64];  // [k][g] swizzled
  int t = threadIdx.x;
  int bo = blockIdx.x & 7;
  int bk = blockIdx.x >> 3;      // 0..249
  int kb = bk * 256;
  int r = t >> 2, q = t & 3;     // staging: row r, k-quarter q (16 k each)
  int to = t & 15, tg = t >> 4;  // compute: o = to*4+j, g = tg*4+m
  float acc[4][4];
#pragma unroll
  for (int j = 0; j < 4; ++j)
#pragma unroll
    for (int m = 0; m < 4; ++m) acc[j][m] = 0.f;

  const float* wrow = W + (size_t)(bo * 64 + r) * 64000 + kb + q * 16;
  const __half* hrow = H + (size_t)r * 64000 + kb + q * 16;

  for (int tile = 0; tile < 4; ++tile) {
    float4 w0 = *(const float4*)(wrow);
    float4 w1 = *(const float4*)(wrow + 4);
    float4 w2 = *(const float4*)(wrow + 8);
    float4 w3 = *(const float4*)(wrow + 12);
    short8 h0 = *(const short8*)(hrow);
    short8 h1 = *(const short8*)(hrow + 8);
    wrow += 64; hrow += 64;
    __syncthreads();  // previous tile reads done
    {
      float wv[16] = {w0.x, w0.y, w0.z, w0.w, w1.x, w1.y, w1.z, w1.w,
                      w2.x, w2.y, w2.z, w2.w, w3.x, w3.y, w3.z, w3.w};
#pragma unroll
      for (int i = 0; i < 16; ++i) {
        int k = q * 16 + i;
        int gcol = (r >> 2) ^ ((k >> 4) << 2);
        int idx = k * 64 + (gcol << 2) + (r & 3);
        As[idx] = wv[i];
        float hvv = h2f(__ushort_as_half(
            (unsigned short)(i < 8 ? h0[i] : h1[i - 8])));
        Bs[idx] = hvv;
      }
    }
    __syncthreads();
#pragma unroll 8
    for (int k = 0; k < 64; ++k) {
      int sw = (k >> 4) << 2;
      float4 a = *(const float4*)&As[k * 64 + ((to ^ sw) << 2)];
      float4 b = *(const float4*)&Bs[k * 64 + ((tg ^ sw) << 2)];
      float av[4] = {a.x, a.y, a.z, a.w};
      float bv[4] = {b.x, b.y, b.z, b.w};
#pragma unroll
      for (int j = 0; j < 4; ++j)
#pragma unroll
        for (int m = 0; m < 4; ++m) acc[j][m] += av[j] * bv[m];
    }
  }
  float* dst = r1p + (size_t)bk * 32768 + (size_t)bo * 4096;
#pragma unroll
  for (int j = 0; j < 4; ++j)
#pragma unroll
    for (int m = 0; m < 4; ++m)
      dst[(to * 4 + j) * 64 + tg * 4 + m] = acc[j][m];
}

// reduce 250 partials, add bias, relu -> r1t[o][g]
__global__ void k_red(const float* __restrict__ r1p, const float* __restrict__ b,
                      float* __restrict__ r1t) {
  int i = blockIdx.x * 256 + threadIdx.x;  // 0..32767
  float s = 0.f;
#pragma unroll 5
  for (int p = 0; p < 250; ++p) s += r1p[(size_t)p * 32768 + i];
  int o = i >> 6;
  r1t[i] = fmaxf(s + b[o], 0.f);
}

__global__ void k_lin2(const float* __restrict__ r1t, const float* __restrict__ W,
                       const float* __restrict__ b, float* __restrict__ r2t) {
  int o = blockIdx.x, g = threadIdx.x;
  float acc = 0.f;
#pragma unroll 4
  for (int i = 0; i < 512; ++i) acc += r1t[i * 64 + g] * W[o * 512 + i];
  r2t[o * 64 + g] = fmaxf(acc + b[o], 0.f);
}

__global__ void k_lin3(const float* __restrict__ r2t, const float* __restrict__ W,
                       const float* __restrict__ b, float* __restrict__ out) {
  int o = blockIdx.x, g = threadIdx.x;
  float acc = 0.f;
#pragma unroll 4
  for (int i = 0; i < 512; ++i) acc += r2t[i * 64 + g] * W[o * 512 + i];
  out[g * 10 + o] = fmaxf(acc + b[o], 0.f);
}

// ---------------- launch ----------------

extern "C" void kernel_launch(void* const* d_in, const int* in_sizes, int n_in,
                              void* d_out, int out_size, void* d_ws, size_t ws_size,
                              hipStream_t stream) {
  const float* x    = (const float*)d_in[0];
  const int*   ei   = (const int*)d_in[1];
  const float* w1_1 = (const float*)d_in[3];  const float* b1_1 = (const float*)d_in[4];
  const float* w1_2 = (const float*)d_in[5];  const float* b1_2 = (const float*)d_in[6];
  const float* w1_3 = (const float*)d_in[7];  const float* b1_3 = (const float*)d_in[8];
  const float* w2_1 = (const float*)d_in[9];  const float* b2_1 = (const float*)d_in[10];
  const float* w2_2 = (const float*)d_in[11]; const float* b2_2 = (const float*)d_in[12];
  const float* w3_1 = (const float*)d_in[13]; const float* b3_1 = (const float*)d_in[14];
  const float* l1w  = (const float*)d_in[15]; const float* l1b  = (const float*)d_in[16];
  const float* l2w  = (const float*)d_in[17]; const float* l2b  = (const float*)d_in[18];
  const float* l3w  = (const float*)d_in[19]; const float* l3b  = (const float*)d_in[20];

  char* ws = (char*)d_ws;
  size_t off = 0;
  auto alloc = [&](size_t bytes) -> char* {
    char* p = ws + off;
    off += (bytes + 255) & ~(size_t)255;
    return p;
  };
  __half* A    = (__half*)alloc((size_t)NN * 64 * 2);
  __half* Bb   = (__half*)alloc((size_t)NN * 64 * 2);
  __half* C    = (__half*)alloc((size_t)NN * 64 * 2);
  __half* T1   = (__half*)alloc((size_t)NN * 64 * 2);
  __half* T2   = (__half*)alloc((size_t)NN * 64 * 2);
  int*   deg  = (int*)alloc(NN * 4);
  float* dis  = (float*)alloc(NN * 4);
  int*   rowp = (int*)alloc((NN + 1) * 4);
  int*   fillp= (int*)alloc(NN * 4);
  unsigned* edata = (unsigned*)alloc((size_t)ET * 4);
  float* t1s  = (float*)alloc(NN * 4);
  float* g2s  = (float*)alloc(NN * 4);
  float* r1t  = (float*)alloc(512 * 64 * 4);
  float* r2t  = (float*)alloc(512 * 64 * 4);
  int*   bsum = (int*)alloc(256 * 4);
  int*   boff = (int*)alloc(256 * 4);
  float* r1p  = (float*)alloc((size_t)250 * 32768 * 4);
  float* wt11 = (float*)alloc(192 * 4);
  float* wt12 = (float*)alloc(12288 * 4);
  float* wt13 = (float*)alloc(12288 * 4);
  float* wt21 = (float*)alloc(12288 * 4);
  float* wt22 = (float*)alloc(12288 * 4);
  float* wt31 = (float*)alloc(12288 * 4);

  hipMemsetAsync(deg, 0, NN * 4, stream);

  k_deg<<<ET / 256, 256, 0, stream>>>(ei, deg);
  k_scan1<<<NN / 256, 256, 0, stream>>>(deg, dis, rowp, bsum);
  k_scan2<<<1, 256, 0, stream>>>(bsum, boff);
  k_scan3<<<NN / 256, 256, 0, stream>>>(rowp, boff, fillp);
  k_fill<<<ET / 256, 256, 0, stream>>>(ei, dis, fillp, edata);

  WXArgs wx{w1_2, w1_3, w2_1, w2_2, w3_1, w1_1,
            wt12, wt13, wt21, wt22, wt31, wt11};
  k_wx<<<81, 256, 0, stream>>>(wx);

  // layer 1 (1 -> 64 channels)
  k_prop_s<<<NN / 256, 256, 0, stream>>>(x, rowp, edata, t1s);
  k_prop_s<<<NN / 256, 256, 0, stream>>>(t1s, rowp, edata, g2s);
  k_layer1<<<NN / 4, 256, 0, stream>>>(x, t1s, g2s, wt11, b1_1, A);

  auto cheb = [&](const __half* in, const float* Wt, const float* bias,
                  int relu_f, const __half* res, __half* out) {
    k_prop64<<<NN / 4, 256, 0, stream>>>(in, rowp, edata, T1);
    k_prop64<<<NN / 4, 256, 0, stream>>>(T1, rowp, edata, T2);
    if (relu_f)
      k_mat64<1, 0><<<NN / 256, 256, 0, stream>>>(in, T1, T2, Wt, bias, nullptr, out);
    else
      k_mat64<0, 1><<<NN / 256, 256, 0, stream>>>(in, T1, T2, Wt, bias, res, out);
  };

  cheb(A,  wt12, b1_2, 1, nullptr, Bb);
  cheb(Bb, wt13, b1_3, 0, A,       C);
  cheb(C,  wt21, b2_1, 1, nullptr, A);
  cheb(A,  wt22, b2_2, 0, C,       Bb);
  cheb(Bb, wt31, b3_1, 1, nullptr, C);   // final H in C

  k_lin1<<<2000, 256, 0, stream>>>(C, l1w, r1p);
  k_red<<<32768 / 256, 256, 0, stream>>>(r1p, l1b, r1t);
  k_lin2<<<512, 64, 0, stream>>>(r1t, l2w, l2b, r2t);
  k_lin3<<<10, 64, 0, stream>>>(r2t, l3w, l3b, (float*)d_out);
}

// Round 7
// 700.234 us; speedup vs baseline: 1.0888x; 1.0888x over previous
//
#include <hip/hip_runtime.h>
#include <hip/hip_fp16.h>

#define NN 64000
#define ET 1024000

typedef __attribute__((ext_vector_type(8))) short short8;
typedef __attribute__((ext_vector_type(8))) _Float16 half8;
typedef __attribute__((ext_vector_type(4))) float f32x4;

__device__ inline float h2f(__half h) { return __half2float(h); }
__device__ inline float dec_w(unsigned p) {
  return __half2float(__ushort_as_half((unsigned short)(p >> 16)));
}

// ---------------- graph build ----------------

__global__ void k_deg(const int* __restrict__ ei, int* __restrict__ deg) {
  int e = blockIdx.x * 256 + threadIdx.x;
  if (e < ET) atomicAdd(&deg[ei[e]], 1);
}

__global__ void k_scan1(const int* __restrict__ deg, float* __restrict__ dis,
                        int* __restrict__ rowp, int* __restrict__ bsum) {
  __shared__ int buf[256];
  int t = threadIdx.x;
  int idx = blockIdx.x * 256 + t;
  int v = deg[idx];
  dis[idx] = v > 0 ? rsqrtf((float)v) : 0.f;
  buf[t] = v;
  __syncthreads();
  for (int off = 1; off < 256; off <<= 1) {
    int x = (t >= off) ? buf[t - off] : 0;
    __syncthreads();
    buf[t] += x;
    __syncthreads();
  }
  rowp[idx] = buf[t] - v;
  if (t == 255) bsum[blockIdx.x] = buf[t];
}

__global__ void k_scan2(const int* __restrict__ bsum, int* __restrict__ boff) {
  __shared__ int buf[256];
  int t = threadIdx.x;
  int v = (t < 250) ? bsum[t] : 0;
  buf[t] = v;
  __syncthreads();
  for (int off = 1; off < 256; off <<= 1) {
    int x = (t >= off) ? buf[t - off] : 0;
    __syncthreads();
    buf[t] += x;
    __syncthreads();
  }
  if (t < 250) boff[t] = buf[t] - v;
}

__global__ void k_scan3(int* __restrict__ rowp, const int* __restrict__ boff,
                        int* __restrict__ fillp) {
  int idx = blockIdx.x * 256 + threadIdx.x;
  int v = rowp[idx] + boff[blockIdx.x];
  rowp[idx] = v;
  fillp[idx] = v;
  if (idx == 0) rowp[NN] = ET;
}

// packed edge record: low16 = src node, high16 = f16 norm
__global__ void k_fill(const int* __restrict__ ei, const float* __restrict__ dis,
                       int* __restrict__ fill_ptr, unsigned* __restrict__ edata) {
  int e = blockIdx.x * 256 + threadIdx.x;
  if (e >= ET) return;
  int s = ei[e];
  int d = ei[ET + e];
  float nrm = -dis[s] * dis[d];
  unsigned packed = (unsigned)s |
      ((unsigned)__half_as_ushort(__float2half(nrm)) << 16);
  int p = atomicAdd(&fill_ptr[d], 1);
  edata[p] = packed;
}

// ---------------- Chebyshev weight fold ----------------
// out = h*W0 + T1*W1 + (2*L*T1 - h)*W2 == h*(W0-W2) + T1*W1 + (L*T1)*(2*W2)

struct WXArgs {
  const float *s0, *s1, *s2, *s3, *s4, *s5;
  float *d0, *d1, *d2, *d3, *d4, *d5;
};

__global__ void k_wx(WXArgs a) {
  int b = blockIdx.x;
  int set = b >> 4;
  const float* s;
  float* d;
  int n = (set < 5) ? 4096 : 64;
  switch (set) {
    case 0: s = a.s0; d = a.d0; break;
    case 1: s = a.s1; d = a.d1; break;
    case 2: s = a.s2; d = a.d2; break;
    case 3: s = a.s3; d = a.d3; break;
    case 4: s = a.s4; d = a.d4; break;
    default: s = a.s5; d = a.d5; break;
  }
  int i = (set < 5) ? (b - set * 16) * 256 + threadIdx.x : threadIdx.x;
  if (i < n) {
    d[i]         = s[i] - s[i + 2 * n];
    d[i + n]     = s[i + n];
    d[i + 2 * n] = 2.f * s[i + 2 * n];
  }
}

// ---------------- scalar (1-channel) plain prop for layer 1 (f32) ----------

__global__ void k_prop_s(const float* __restrict__ in, const int* __restrict__ row_ptr,
                         const unsigned* __restrict__ edata, float* __restrict__ out) {
  int n = blockIdx.x * 256 + threadIdx.x;
  if (n >= NN) return;
  int s = row_ptr[n], e = row_ptr[n + 1];
  float acc = 0.f;
  int j = s;
  for (; j + 4 <= e; j += 4) {
    unsigned e0 = edata[j], e1 = edata[j + 1], e2 = edata[j + 2], e3 = edata[j + 3];
    acc += in[e0 & 0xFFFFu] * dec_w(e0) + in[e1 & 0xFFFFu] * dec_w(e1) +
           in[e2 & 0xFFFFu] * dec_w(e2) + in[e3 & 0xFFFFu] * dec_w(e3);
  }
  for (; j < e; ++j) {
    unsigned e0 = edata[j];
    acc += in[e0 & 0xFFFFu] * dec_w(e0);
  }
  out[n] = acc;
}

__global__ void k_layer1(const float* __restrict__ x, const float* __restrict__ t1,
                         const float* __restrict__ g2, const float* __restrict__ w,
                         const float* __restrict__ b, __half* __restrict__ out) {
  int t = threadIdx.x;
  int node = blockIdx.x * 4 + (t >> 6);
  int f = t & 63;
  float v = x[node] * w[f] + t1[node] * w[64 + f] + g2[node] * w[128 + f] + b[f];
  out[(size_t)node * 64 + f] = __float2half(fmaxf(v, 0.f));
}

// ---------------- 64-channel plain prop (f16 features): wave/node, lane=feat
// (round-5 version: 16-deep gather ladder, one 128B line per gather instr)

__global__ __launch_bounds__(256) void k_prop64(const __half* __restrict__ in,
    const int* __restrict__ row_ptr, const unsigned* __restrict__ edata,
    __half* __restrict__ out) {
  int node = __builtin_amdgcn_readfirstlane(blockIdx.x * 4 + (threadIdx.x >> 6));
  int f = threadIdx.x & 63;
  int s = row_ptr[node], e = row_ptr[node + 1];
  float a[16];
#pragma unroll
  for (int i = 0; i < 16; ++i) a[i] = 0.f;
  int j = s;
  for (; j + 16 <= e; j += 16) {
    unsigned ed[16];
#pragma unroll
    for (int i = 0; i < 16; ++i) ed[i] = edata[j + i];
    float v[16];
#pragma unroll
    for (int i = 0; i < 16; ++i) v[i] = h2f(in[(size_t)(ed[i] & 0xFFFFu) * 64 + f]);
#pragma unroll
    for (int i = 0; i < 16; ++i) a[i] += v[i] * dec_w(ed[i]);
  }
  for (; j + 8 <= e; j += 8) {
    unsigned ed[8];
#pragma unroll
    for (int i = 0; i < 8; ++i) ed[i] = edata[j + i];
    float v[8];
#pragma unroll
    for (int i = 0; i < 8; ++i) v[i] = h2f(in[(size_t)(ed[i] & 0xFFFFu) * 64 + f]);
#pragma unroll
    for (int i = 0; i < 8; ++i) a[i] += v[i] * dec_w(ed[i]);
  }
  for (; j + 4 <= e; j += 4) {
    unsigned ed[4];
#pragma unroll
    for (int i = 0; i < 4; ++i) ed[i] = edata[j + i];
    float v[4];
#pragma unroll
    for (int i = 0; i < 4; ++i) v[i] = h2f(in[(size_t)(ed[i] & 0xFFFFu) * 64 + f]);
#pragma unroll
    for (int i = 0; i < 4; ++i) a[i] += v[i] * dec_w(ed[i]);
  }
  for (; j < e; ++j) {
    unsigned e0 = edata[j];
    a[0] += h2f(in[(size_t)(e0 & 0xFFFFu) * 64 + f]) * dec_w(e0);
  }
#pragma unroll
  for (int i = 0; i < 8; ++i) a[i] += a[i + 8];
#pragma unroll
  for (int i = 0; i < 4; ++i) a[i] += a[i + 4];
  float acc = (a[0] + a[1]) + (a[2] + a[3]);
  out[(size_t)node * 64 + f] = __float2half(acc);
}

// ------- fused cheb matmul: out = T0@W0' + T1@W1' + G2@W2' (+b, relu/res), f16 IO

template<int RELU, int RES>
__global__ __launch_bounds__(256) void k_mat64(
    const __half* __restrict__ T0, const __half* __restrict__ T1,
    const __half* __restrict__ T2, const float* __restrict__ W,
    const float* __restrict__ bias, const __half* __restrict__ res,
    __half* __restrict__ out) {
  __shared__ float Ws[3 * 64 * 64];
  __shared__ float As[256 * 21];
  int t = threadIdx.x;
  int node0 = blockIdx.x * 256;
  {
    const float4* Wv = (const float4*)W;
    float4* Sv = (float4*)Ws;
    for (int i = t; i < 3072; i += 256) Sv[i] = Wv[i];
  }
  int fi = t & 7;
  int ni = t >> 3;
  float acc[8][8];
#pragma unroll
  for (int j = 0; j < 8; ++j)
#pragma unroll
    for (int m = 0; m < 8; ++m) acc[j][m] = 0.f;

  for (int p = 0; p < 12; ++p) {
    int k = p >> 2, c0 = (p & 3) << 4;
    const __half* Tsel = (k == 0) ? T0 : (k == 1) ? T1 : T2;
    const __half* src = Tsel + (size_t)(node0 + t) * 64 + c0;
    short8 r0 = *(const short8*)(src);
    short8 r1 = *(const short8*)(src + 8);
    __syncthreads();
    float* dst = &As[t * 21];
#pragma unroll
    for (int i = 0; i < 8; ++i) dst[i] = h2f(__ushort_as_half((unsigned short)r0[i]));
#pragma unroll
    for (int i = 0; i < 8; ++i) dst[8 + i] = h2f(__ushort_as_half((unsigned short)r1[i]));
    __syncthreads();
#pragma unroll
    for (int cc = 0; cc < 16; ++cc) {
      int c = c0 + cc;
      float a[8], bb[8];
#pragma unroll
      for (int j = 0; j < 8; ++j) a[j] = As[(ni + 32 * j) * 21 + cc];
      const float* wrow = &Ws[k * 4096 + c * 64];
#pragma unroll
      for (int m = 0; m < 8; ++m) bb[m] = wrow[fi + 8 * m];
#pragma unroll
      for (int j = 0; j < 8; ++j)
#pragma unroll
        for (int m = 0; m < 8; ++m) acc[j][m] += a[j] * bb[m];
    }
  }
#pragma unroll
  for (int j = 0; j < 8; ++j) {
    int node = node0 + ni + 32 * j;
#pragma unroll
    for (int m = 0; m < 8; ++m) {
      int f = fi + 8 * m;
      float v = acc[j][m] + bias[f];
      if (RES) v += h2f(res[(size_t)node * 64 + f]);
      if (RELU) v = fmaxf(v, 0.f);
      out[(size_t)node * 64 + f] = __float2half(v);
    }
  }
}

// ---------------- readout ----------------
// lin1 partials via MFMA: C[o][g] = sum_k W[o][k] * H[g][k].
// grid = 8 o-blocks x 250 k-splits (256 k each). Per block: H chunk staged
// to LDS fp16 [64][264]; W f32 read direct from global (wave covers 16 rows
// x 128B full lines), cvt to f16 in regs; 4 waves x 8 ksteps x 4 MFMA
// (v_mfma_f32_16x16x32_f16). A row=lane&15, k=8*(lane>>4)+j; B col=lane&15;
// D col=lane&15(g), row=4*(lane>>4)+reg (o).

__global__ __launch_bounds__(256) void k_lin1(const __half* __restrict__ H,
    const float* __restrict__ W, float* __restrict__ r1p) {
  __shared__ _Float16 Hs[64][264];
  int t = threadIdx.x;
  int bo = blockIdx.x & 7;
  int bk = blockIdx.x >> 3;      // 0..249
  int kb = bk * 256;
  {
    int g = t >> 2, ks = (t & 3) * 64;
    const short8* src = (const short8*)(H + (size_t)g * 64000 + kb + ks);
#pragma unroll
    for (int i = 0; i < 8; ++i) {
      short8 v = src[i];
      *(short8*)&Hs[g][ks + i * 8] = v;
    }
  }
  __syncthreads();

  int wv = t >> 6, lane = t & 63;
  int arow = lane & 15, kgrp = (lane >> 4) * 8;
  f32x4 acc0 = {0.f, 0.f, 0.f, 0.f};
  f32x4 acc1 = {0.f, 0.f, 0.f, 0.f};
  f32x4 acc2 = {0.f, 0.f, 0.f, 0.f};
  f32x4 acc3 = {0.f, 0.f, 0.f, 0.f};

  const float* wp = W + (size_t)(bo * 64 + wv * 16 + arow) * 64000 + kb + kgrp;
#pragma unroll
  for (int kstep = 0; kstep < 8; ++kstep) {
    f32x4 w0 = *(const f32x4*)(wp);
    f32x4 w1 = *(const f32x4*)(wp + 4);
    wp += 32;
    half8 a;
    a[0] = (_Float16)w0[0]; a[1] = (_Float16)w0[1];
    a[2] = (_Float16)w0[2]; a[3] = (_Float16)w0[3];
    a[4] = (_Float16)w1[0]; a[5] = (_Float16)w1[1];
    a[6] = (_Float16)w1[2]; a[7] = (_Float16)w1[3];
    int kk = kstep * 32 + kgrp;
    half8 b0 = *(const half8*)&Hs[arow][kk];
    half8 b1 = *(const half8*)&Hs[16 + arow][kk];
    half8 b2 = *(const half8*)&Hs[32 + arow][kk];
    half8 b3 = *(const half8*)&Hs[48 + arow][kk];
    acc0 = __builtin_amdgcn_mfma_f32_16x16x32_f16(a, b0, acc0, 0, 0, 0);
    acc1 = __builtin_amdgcn_mfma_f32_16x16x32_f16(a, b1, acc1, 0, 0, 0);
    acc2 = __builtin_amdgcn_mfma_f32_16x16x32_f16(a, b2, acc2, 0, 0, 0);
    acc3 = __builtin_amdgcn_mfma_f32_16x16x32_f16(a, b3, acc3, 0, 0, 0);
  }

  // write 64x64 partial tile: r1p[bk][512 o][64 g]
  float* dst = r1p + (size_t)bk * 32768;
  int orow = bo * 64 + wv * 16 + (lane >> 4) * 4;
  int g = lane & 15;
#pragma unroll
  for (int reg = 0; reg < 4; ++reg) {
    dst[(orow + reg) * 64 + g]      = acc0[reg];
    dst[(orow + reg) * 64 + 16 + g] = acc1[reg];
    dst[(orow + reg) * 64 + 32 + g] = acc2[reg];
    dst[(orow + reg) * 64 + 48 + g] = acc3[reg];
  }
}

// reduce 250 partials, add bias, relu -> r1t[o][g]
__global__ void k_red(const float* __restrict__ r1p, const float* __restrict__ b,
                      float* __restrict__ r1t) {
  int i = blockIdx.x * 256 + threadIdx.x;  // 0..32767
  float s = 0.f;
#pragma unroll 5
  for (int p = 0; p < 250; ++p) s += r1p[(size_t)p * 32768 + i];
  int o = i >> 6;
  r1t[i] = fmaxf(s + b[o], 0.f);
}

__global__ void k_lin2(const float* __restrict__ r1t, const float* __restrict__ W,
                       const float* __restrict__ b, float* __restrict__ r2t) {
  int o = blockIdx.x, g = threadIdx.x;
  float acc = 0.f;
#pragma unroll 4
  for (int i = 0; i < 512; ++i) acc += r1t[i * 64 + g] * W[o * 512 + i];
  r2t[o * 64 + g] = fmaxf(acc + b[o], 0.f);
}

__global__ void k_lin3(const float* __restrict__ r2t, const float* __restrict__ W,
                       const float* __restrict__ b, float* __restrict__ out) {
  int o = blockIdx.x, g = threadIdx.x;
  float acc = 0.f;
#pragma unroll 4
  for (int i = 0; i < 512; ++i) acc += r2t[i * 64 + g] * W[o * 512 + i];
  out[g * 10 + o] = fmaxf(acc + b[o], 0.f);
}

// ---------------- launch ----------------

extern "C" void kernel_launch(void* const* d_in, const int* in_sizes, int n_in,
                              void* d_out, int out_size, void* d_ws, size_t ws_size,
                              hipStream_t stream) {
  const float* x    = (const float*)d_in[0];
  const int*   ei   = (const int*)d_in[1];
  const float* w1_1 = (const float*)d_in[3];  const float* b1_1 = (const float*)d_in[4];
  const float* w1_2 = (const float*)d_in[5];  const float* b1_2 = (const float*)d_in[6];
  const float* w1_3 = (const float*)d_in[7];  const float* b1_3 = (const float*)d_in[8];
  const float* w2_1 = (const float*)d_in[9];  const float* b2_1 = (const float*)d_in[10];
  const float* w2_2 = (const float*)d_in[11]; const float* b2_2 = (const float*)d_in[12];
  const float* w3_1 = (const float*)d_in[13]; const float* b3_1 = (const float*)d_in[14];
  const float* l1w  = (const float*)d_in[15]; const float* l1b  = (const float*)d_in[16];
  const float* l2w  = (const float*)d_in[17]; const float* l2b  = (const float*)d_in[18];
  const float* l3w  = (const float*)d_in[19]; const float* l3b  = (const float*)d_in[20];

  char* ws = (char*)d_ws;
  size_t off = 0;
  auto alloc = [&](size_t bytes) -> char* {
    char* p = ws + off;
    off += (bytes + 255) & ~(size_t)255;
    return p;
  };
  __half* A    = (__half*)alloc((size_t)NN * 64 * 2);
  __half* Bb   = (__half*)alloc((size_t)NN * 64 * 2);
  __half* C    = (__half*)alloc((size_t)NN * 64 * 2);
  __half* T1   = (__half*)alloc((size_t)NN * 64 * 2);
  __half* T2   = (__half*)alloc((size_t)NN * 64 * 2);
  int*   deg  = (int*)alloc(NN * 4);
  float* dis  = (float*)alloc(NN * 4);
  int*   rowp = (int*)alloc((NN + 1) * 4);
  int*   fillp= (int*)alloc(NN * 4);
  unsigned* edata = (unsigned*)alloc((size_t)ET * 4);
  float* t1s  = (float*)alloc(NN * 4);
  float* g2s  = (float*)alloc(NN * 4);
  float* r1t  = (float*)alloc(512 * 64 * 4);
  float* r2t  = (float*)alloc(512 * 64 * 4);
  int*   bsum = (int*)alloc(256 * 4);
  int*   boff = (int*)alloc(256 * 4);
  float* r1p  = (float*)alloc((size_t)250 * 32768 * 4);
  float* wt11 = (float*)alloc(192 * 4);
  float* wt12 = (float*)alloc(12288 * 4);
  float* wt13 = (float*)alloc(12288 * 4);
  float* wt21 = (float*)alloc(12288 * 4);
  float* wt22 = (float*)alloc(12288 * 4);
  float* wt31 = (float*)alloc(12288 * 4);

  hipMemsetAsync(deg, 0, NN * 4, stream);

  k_deg<<<ET / 256, 256, 0, stream>>>(ei, deg);
  k_scan1<<<NN / 256, 256, 0, stream>>>(deg, dis, rowp, bsum);
  k_scan2<<<1, 256, 0, stream>>>(bsum, boff);
  k_scan3<<<NN / 256, 256, 0, stream>>>(rowp, boff, fillp);
  k_fill<<<ET / 256, 256, 0, stream>>>(ei, dis, fillp, edata);

  WXArgs wx{w1_2, w1_3, w2_1, w2_2, w3_1, w1_1,
            wt12, wt13, wt21, wt22, wt31, wt11};
  k_wx<<<81, 256, 0, stream>>>(wx);

  // layer 1 (1 -> 64 channels)
  k_prop_s<<<NN / 256, 256, 0, stream>>>(x, rowp, edata, t1s);
  k_prop_s<<<NN / 256, 256, 0, stream>>>(t1s, rowp, edata, g2s);
  k_layer1<<<NN / 4, 256, 0, stream>>>(x, t1s, g2s, wt11, b1_1, A);

  auto cheb = [&](const __half* in, const float* Wt, const float* bias,
                  int relu_f, const __half* res, __half* out) {
    k_prop64<<<NN / 4, 256, 0, stream>>>(in, rowp, edata, T1);
    k_prop64<<<NN / 4, 256, 0, stream>>>(T1, rowp, edata, T2);
    if (relu_f)
      k_mat64<1, 0><<<NN / 256, 256, 0, stream>>>(in, T1, T2, Wt, bias, nullptr, out);
    else
      k_mat64<0, 1><<<NN / 256, 256, 0, stream>>>(in, T1, T2, Wt, bias, res, out);
  };

  cheb(A,  wt12, b1_2, 1, nullptr, Bb);
  cheb(Bb, wt13, b1_3, 0, A,       C);
  cheb(C,  wt21, b2_1, 1, nullptr, A);
  cheb(A,  wt22, b2_2, 0, C,       Bb);
  cheb(Bb, wt31, b3_1, 1, nullptr, C);   // final H in C

  k_lin1<<<2000, 256, 0, stream>>>(C, l1w, r1p);
  k_red<<<32768 / 256, 256, 0, stream>>>(r1p, l1b, r1t);
  k_lin2<<<512, 64, 0, stream>>>(r1t, l2w, l2b, r2t);
  k_lin3<<<10, 64, 0, stream>>>(r2t, l3w, l3b, (float*)d_out);
}